// Round 16
// baseline (59.209 us; speedup 1.0000x reference)
//
#include <hip/hip_runtime.h>
#include <hip/hip_bf16.h>

#define B_ 8
#define C_ 256
#define L_ 1024
#define NH_ 8
#define EPS_ 1e-5f

typedef __attribute__((ext_vector_type(8))) _Float16 half8;
typedef __attribute__((ext_vector_type(2))) __fp16 fp16x2;
typedef __attribute__((ext_vector_type(4))) float f32x4;

static __device__ inline ushort f2h(float f) {
  union { _Float16 h; ushort u; } c;
  c.h = (_Float16)f;
  return c.u;
}

// pack two fp32 -> fp16 pair via v_cvt_pkrtz_f16_f32 (compiler builtin --
// safe on TRANS-result inputs, unlike inline asm; rounds 9-11 lesson)
static __device__ inline uint pkh(float a, float b) {
  union { fp16x2 v; uint u; } c;
  c.v = __builtin_amdgcn_cvt_pkrtz(a, b);
  return c.u;
}

// ---------------------------------------------------------------------------
// Kernel A (512 threads): blocks 0-127: weight fp32->fp16 convert;
// blocks 128-383: GroupNorm + depthwise conv k=3. ht [B][32 cg][1024 l][8 c].
// ---------------------------------------------------------------------------
__global__ __launch_bounds__(512) void gnw_kernel(
    const float* __restrict__ x, const float* __restrict__ gamma,
    const float* __restrict__ beta, const float* __restrict__ dw,
    const float4* __restrict__ qw, const float4* __restrict__ ow,
    uint2* __restrict__ wq, uint2* __restrict__ wo_,
    ushort* __restrict__ ht) {
  __shared__ float hn[8 * L_];
  __shared__ float ws0[8], ws1[8];
  int t = threadIdx.x;
  if (blockIdx.x < 128) {
    int id = blockIdx.x * 512 + t;
    float4 v;
    uint2* dst;
    if (id < 49152) { v = qw[id]; dst = wq + id; }
    else { v = ow[id - 49152]; dst = wo_ + (id - 49152); }
    *dst = make_uint2(pkh(v.x, v.y), pkh(v.z, v.w));
    return;
  }
  int blk = blockIdx.x - 128;     // b*32 + g
  int b = blk >> 5, g = blk & 31;
  const size_t base = ((size_t)(b * C_ + g * 8)) * L_;

  float s = 0.f, ss = 0.f;
  float vals[16];
#pragma unroll
  for (int i = 0; i < 16; ++i) {
    int e = t + 512 * i;
    float v = x[base + e];
    vals[i] = v;
    s += v; ss += v * v;
  }
#pragma unroll
  for (int off = 32; off >= 1; off >>= 1) {
    s  += __shfl_xor(s, off);
    ss += __shfl_xor(ss, off);
  }
  int wave = t >> 6;
  if ((t & 63) == 0) { ws0[wave] = s; ws1[wave] = ss; }
  __syncthreads();
  s = 0.f; ss = 0.f;
#pragma unroll
  for (int i = 0; i < 8; ++i) { s += ws0[i]; ss += ws1[i]; }
  float mean = s * (1.f / 8192.f);
  float var = ss * (1.f / 8192.f) - mean * mean;
  float rstd = rsqrtf(var + EPS_);

#pragma unroll
  for (int i = 0; i < 16; ++i) {
    int e = t + 512 * i;
    int c = g * 8 + (i >> 1);
    float sc = gamma[c] * rstd;
    hn[e] = (vals[i] - mean) * sc + beta[c];
  }
  __syncthreads();
  float r[16];
#pragma unroll
  for (int i = 0; i < 16; ++i) {
    int e = t + 512 * i;
    int l = e & 1023;
    int c = g * 8 + (i >> 1);
    float w0 = dw[c * 3 + 0], w1 = dw[c * 3 + 1], w2 = dw[c * 3 + 2];
    float a = (l > 0) ? hn[e - 1] : 0.f;
    float m = hn[e];
    float z = (l < 1023) ? hn[e + 1] : 0.f;
    r[i] = w0 * a + w1 * m + w2 * z;
  }
#pragma unroll
  for (int li = 0; li < 2; ++li) {
    int l = t + 512 * li;
    uint4 pk;
    pk.x = pkh(r[0 + li],  r[2 + li]);
    pk.y = pkh(r[4 + li],  r[6 + li]);
    pk.z = pkh(r[8 + li],  r[10 + li]);
    pk.w = pkh(r[12 + li], r[14 + li]);
    *(uint4*)(ht + (((size_t)(b * 32 + g)) * L_ + l) * 8) = pk;
  }
}

// ---------------------------------------------------------------------------
// Kernel B: qkv pointwise conv via MFMA (fp16), fused repack epilogue.
// Input ht [B][32][1024][8]. Q PRE-SCALED by 1/sqrt(C)*log2(e).
// ---------------------------------------------------------------------------
__global__ __launch_bounds__(256) void qkv_fused_kernel(
    const ushort* __restrict__ Xt, const ushort* __restrict__ Wb,
    const float* __restrict__ bias, ushort* __restrict__ qt,
    ushort* __restrict__ kt, ushort* __restrict__ vb) {
  int bx = blockIdx.x, head = blockIdx.y, b = blockIdx.z;
  int bh = b * 8 + head;
  int t = threadIdx.x;
  int w = t >> 6, l = t & 63;
  int g = l >> 4, ln = l & 15;
  int wl = w >> 1, wo = w & 1;
  int lbase = bx * 128 + wl * 64;

  const ushort* xb = Xt + (size_t)b * (32 * L_ * 8);
  const ushort* wp = Wb + (size_t)(head * 96 + wo * 48) * 256;

  f32x4 acc[4][3];
#pragma unroll
  for (int ml = 0; ml < 4; ++ml)
#pragma unroll
    for (int nn = 0; nn < 3; ++nn) acc[ml][nn] = (f32x4){0.f, 0.f, 0.f, 0.f};

  for (int c0 = 0; c0 < 256; c0 += 32) {
    half8 af[4], bf[3];
#pragma unroll
    for (int ml = 0; ml < 4; ++ml)
      af[ml] = *(const half8*)(xb +
          (((size_t)((c0 >> 3) + g)) * L_ + lbase + 16 * ml + ln) * 8);
#pragma unroll
    for (int nn = 0; nn < 3; ++nn)
      bf[nn] = *(const half8*)(wp + (size_t)(16 * nn + ln) * 256 + c0 + 8 * g);
#pragma unroll
    for (int ml = 0; ml < 4; ++ml)
#pragma unroll
      for (int nn = 0; nn < 3; ++nn)
        acc[ml][nn] = __builtin_amdgcn_mfma_f32_16x16x32_f16(af[ml], bf[nn], acc[ml][nn], 0, 0, 0);
  }

  // bias
#pragma unroll
  for (int nn = 0; nn < 3; ++nn) {
    float bs = bias[head * 96 + wo * 48 + 16 * nn + ln];
#pragma unroll
    for (int ml = 0; ml < 4; ++ml)
#pragma unroll
      for (int r = 0; r < 4; ++r) acc[ml][nn][r] += bs;
  }

  __shared__ ushort tr[5120];
  const float QSC = 0.0625f * 1.44269504f;   // 1/sqrt(256) * log2(e)

  // rounds 0 (q, scaled), 1 (k): transpose to [l][d] (pad 40), write [bh][l][32]
  for (int rk = 0; rk < 2; ++rk) {
    float sc = rk ? 1.f : QSC;
    __syncthreads();
#pragma unroll
    for (int nn = 0; nn < 3; ++nn) {
      int ocl0 = wo * 48 + 16 * nn;
      if (ocl0 >= rk * 32 && ocl0 < rk * 32 + 32) {
        int d = ocl0 - rk * 32 + ln;
#pragma unroll
        for (int ml = 0; ml < 4; ++ml) {
          int lrow = wl * 64 + 16 * ml + 4 * g;
#pragma unroll
          for (int r = 0; r < 4; ++r)
            tr[(lrow + r) * 40 + d] = f2h(acc[ml][nn][r] * sc);
        }
      }
    }
    __syncthreads();
    {
      int row = t >> 1, half = t & 1;
      uint4 v0 = *(const uint4*)&tr[row * 40 + half * 16];
      uint4 v1 = *(const uint4*)&tr[row * 40 + half * 16 + 8];
      ushort* dst = (rk ? kt : qt) +
                    ((size_t)bh * L_ + bx * 128 + row) * 32 + half * 16;
      *(uint4*)dst = v0;
      *(uint4*)(dst + 8) = v1;
    }
  }

  // round 2 (v): [d][l] (pad 136), PI-permute on global write
  __syncthreads();
  if (wo == 1) {
#pragma unroll
    for (int nn = 1; nn < 3; ++nn) {
      int d = 16 * (nn - 1) + ln;
#pragma unroll
      for (int ml = 0; ml < 4; ++ml) {
        int lc = wl * 64 + 16 * ml + 4 * g;
        *(uint2*)&tr[d * 136 + lc] =
            make_uint2(pkh(acc[ml][nn][0], acc[ml][nn][1]),
                       pkh(acc[ml][nn][2], acc[ml][nn][3]));
      }
    }
  }
  __syncthreads();
  {
    int d = t >> 3, s0 = t & 7;
    ushort* vdst = vb + ((size_t)bh * 32 + d) * L_ + bx * 128;
#pragma unroll
    for (int c = 0; c < 2; ++c) {
      int ch = s0 + 8 * c;
      int jj = ch >> 2, gg = ch & 3;
      uint2 lo = *(const uint2*)&tr[d * 136 + 32 * jj + 4 * gg];
      uint2 hi = *(const uint2*)&tr[d * 136 + 32 * jj + 16 + 4 * gg];
      *(uint4*)(vdst + 32 * jj + 8 * gg) = make_uint4(lo.x, lo.y, hi.x, hi.y);
    }
  }
}

// ---------------------------------------------------------------------------
// Kernel D: out pointwise conv via MFMA (fp16) + residual. Input ot
// [bh][1024][32]. Block = 128 l x 64 oc. grid (8, 4, B) = 256.
// ---------------------------------------------------------------------------
__global__ __launch_bounds__(256) void outconv_kernel(
    const ushort* __restrict__ Xt, const ushort* __restrict__ Wb,
    const float* __restrict__ bias, const float* __restrict__ resid,
    float* __restrict__ out) {
  int b = blockIdx.z;
  int t = threadIdx.x;
  int w = t >> 6, l = t & 63;
  int g = l >> 4, ln = l & 15;
  int lbase = blockIdx.x * 128;
  int ocblk = blockIdx.y * 64;
  int ocbase = ocblk + w * 16;

  const ushort* xb = Xt + (size_t)b * (8 * L_ * 32);
  const ushort* wp = Wb + (size_t)ocbase * 256;

  f32x4 acc[8];
#pragma unroll
  for (int ml = 0; ml < 8; ++ml) acc[ml] = (f32x4){0.f, 0.f, 0.f, 0.f};

  for (int c0 = 0; c0 < 256; c0 += 32) {
    half8 af[8];
#pragma unroll
    for (int ml = 0; ml < 8; ++ml)
      af[ml] = *(const half8*)(xb +
          ((size_t)(c0 >> 5) * L_ + lbase + 16 * ml + ln) * 32 + 8 * g);
    half8 bf = *(const half8*)(wp + (size_t)ln * 256 + c0 + 8 * g);
#pragma unroll
    for (int ml = 0; ml < 8; ++ml)
      acc[ml] = __builtin_amdgcn_mfma_f32_16x16x32_f16(af[ml], bf, acc[ml], 0, 0, 0);
  }

  __shared__ float tile[64][132];   // 33 KB
  float bs = bias[ocbase + ln];
#pragma unroll
  for (int ml = 0; ml < 8; ++ml) {
    int ll = 16 * ml + 4 * g;
    float4 v = make_float4(acc[ml][0] + bs, acc[ml][1] + bs,
                           acc[ml][2] + bs, acc[ml][3] + bs);
    *(float4*)&tile[w * 16 + ln][ll] = v;
  }
  __syncthreads();
  {
    int ocl = t >> 2, lq = t & 3;           // 64 oc x 4 l-chunks of 32
    const float* src = &tile[ocl][lq * 32];
    size_t ob = ((size_t)b * 256 + ocblk + ocl) * L_ + lbase + lq * 32;
#pragma unroll
    for (int i = 0; i < 8; ++i) {
      float4 v = *(const float4*)(src + 4 * i);
      float4 rd = *(const float4*)(resid + ob + 4 * i);
      v.x += rd.x; v.y += rd.y; v.z += rd.z; v.w += rd.w;
      *(float4*)(out + ob + 4 * i) = v;
    }
  }
}

// ---------------------------------------------------------------------------
// Kernel C: MFMA flash attention, kv-SPLIT: 512 threads = 2 quads of 4 waves;
// quad q handles kv [512q, 512q+512) for the same 128 q-rows (no-max softmax
// makes kv tiles independent -- partials just sum). K dbuf LDS per quad;
// V read direct from global (PI-permuted layout = contiguous 16B fragments,
// L2-resident). Epilogue combines quad partials in LDS. grid 512 -> 4 w/SIMD.
// ---------------------------------------------------------------------------
__global__ __launch_bounds__(512) void attn_mfma_kernel(
    const ushort* __restrict__ qt, const ushort* __restrict__ kt,
    const ushort* __restrict__ vb, ushort* __restrict__ ot) {
  const int id = blockIdx.x;
  const int bh = ((id & 7) << 3) | (id >> 6);
  const int qtile = (id >> 3) & 7;
  const int t = threadIdx.x;
  const int w = t >> 6, l = t & 63;
  const int g = l >> 4, ln = l & 15;
  const int quad = w >> 2, wq = w & 3;
  const int q0b = qtile * 128;
  const int q0 = q0b + wq * 32;
  const int kvbase = quad * 512;

  // smem (ushorts): quad0 K dbuf @0 (2x5120), quad1 K dbuf @10240 (2x5120).
  // epilogue overlays: otile [128][40]=5120 @0; Of fp32 [128][33] @10240;
  // Df fp32 [128] @18688. total 40,960 B.
  __shared__ __align__(16) ushort smem[20480];

  const ushort* qbase = qt + (size_t)bh * (L_ * 32);
  const ushort* kbase = kt + (size_t)bh * (L_ * 32);
  const ushort* vbase = vb + (size_t)bh * (32 * L_);

  // K staging geometry (256 threads per quad)
  const int tq = t & 255;
  const int krow = tq >> 1, khalf = tq & 1;
  const ushort* kg = kbase + (size_t)(kvbase + krow) * 32 + khalf * 16;
  const int kldsbase = quad * 10240;
  const int kwo = krow * 40 + khalf * 16;

  const f32x4 z4 = {0.f, 0.f, 0.f, 0.f};
  half8 bq[2];
  bq[0] = *(const half8*)(qbase + (size_t)(q0 + ln) * 32 + g * 8);
  bq[1] = *(const half8*)(qbase + (size_t)(q0 + 16 + ln) * 32 + g * 8);

  union { ushort s[8]; half8 v; } onesu;
#pragma unroll
  for (int i = 0; i < 8; ++i) onesu.s[i] = 0x3C00;  // fp16 1.0
  const half8 ones = onesu.v;

  f32x4 oacc[2][2];  // [md][nq]
  oacc[0][0] = z4; oacc[0][1] = z4; oacc[1][0] = z4; oacc[1][1] = z4;
  f32x4 oaccS[2] = {z4, z4};

  // prologue: stage K tile 0
  uint4 ka0, ka1;
  ka0 = *(const uint4*)kg;       ka1 = *(const uint4*)(kg + 8);
  __builtin_amdgcn_sched_barrier(0);
  *(uint4*)&smem[kldsbase + kwo] = ka0;
  *(uint4*)&smem[kldsbase + kwo + 8] = ka1;
  asm volatile("s_waitcnt lgkmcnt(0)" ::: "memory");
  __builtin_amdgcn_s_barrier();
  __builtin_amdgcn_sched_barrier(0);

  for (int tt = 0; tt < 4; ++tt) {
    const int cur = tt & 1;
    if (tt < 3) {
      ka0 = *(const uint4*)(kg + (tt + 1) * 4096);
      ka1 = *(const uint4*)(kg + (tt + 1) * 4096 + 8);
    }
    __builtin_amdgcn_sched_barrier(0);

    const ushort* Kc = &smem[kldsbase + cur * 5120];

    // QK^T  (S in log2-units via Q pre-scale)
    f32x4 sacc[8][2];
#pragma unroll
    for (int mk = 0; mk < 8; ++mk) {
      half8 ak = *(const half8*)(Kc + (16 * mk + ln) * 40 + g * 8);
      sacc[mk][0] = __builtin_amdgcn_mfma_f32_16x16x32_f16(ak, bq[0], z4, 0, 0, 0);
      sacc[mk][1] = __builtin_amdgcn_mfma_f32_16x16x32_f16(ak, bq[1], z4, 0, 0, 0);
    }

    // exp via v_exp_f32; pack via cvt_pkrtz builtin (safe TRANS consumer)
    uint upk[2][8][2];
#pragma unroll
    for (int nq = 0; nq < 2; ++nq) {
#pragma unroll
      for (int mk = 0; mk < 8; ++mk) {
        float e0 = __builtin_amdgcn_exp2f(sacc[mk][nq][0]);
        float e1 = __builtin_amdgcn_exp2f(sacc[mk][nq][1]);
        float e2 = __builtin_amdgcn_exp2f(sacc[mk][nq][2]);
        float e3 = __builtin_amdgcn_exp2f(sacc[mk][nq][3]);
        upk[nq][mk][0] = pkh(e0, e1);
        upk[nq][mk][1] = pkh(e2, e3);
      }
    }

    // PV + denominator; V direct from global (PI-permuted, contiguous 16B)
    const ushort* vt = vbase + kvbase + tt * 128;
    __builtin_amdgcn_s_setprio(1);
#pragma unroll
    for (int ks = 0; ks < 4; ++ks) {
      union { uint u[4]; half8 v; } pb0, pb1;
      pb0.u[0] = upk[0][2 * ks][0]; pb0.u[1] = upk[0][2 * ks][1];
      pb0.u[2] = upk[0][2 * ks + 1][0]; pb0.u[3] = upk[0][2 * ks + 1][1];
      pb1.u[0] = upk[1][2 * ks][0]; pb1.u[1] = upk[1][2 * ks][1];
      pb1.u[2] = upk[1][2 * ks + 1][0]; pb1.u[3] = upk[1][2 * ks + 1][1];
      oaccS[0] = __builtin_amdgcn_mfma_f32_16x16x32_f16(ones, pb0.v, oaccS[0], 0, 0, 0);
      oaccS[1] = __builtin_amdgcn_mfma_f32_16x16x32_f16(ones, pb1.v, oaccS[1], 0, 0, 0);
#pragma unroll
      for (int md = 0; md < 2; ++md) {
        half8 av = *(const half8*)(vt + (size_t)(16 * md + ln) * L_ + 32 * ks + 8 * g);
        oacc[md][0] = __builtin_amdgcn_mfma_f32_16x16x32_f16(av, pb0.v, oacc[md][0], 0, 0, 0);
        oacc[md][1] = __builtin_amdgcn_mfma_f32_16x16x32_f16(av, pb1.v, oacc[md][1], 0, 0, 0);
      }
    }
    __builtin_amdgcn_s_setprio(0);

    __builtin_amdgcn_sched_barrier(0);
    if (tt < 3) {
      const int nxt = cur ^ 1;
      *(uint4*)&smem[kldsbase + nxt * 5120 + kwo] = ka0;
      *(uint4*)&smem[kldsbase + nxt * 5120 + kwo + 8] = ka1;
      asm volatile("s_waitcnt lgkmcnt(0)" ::: "memory");
      __builtin_amdgcn_s_barrier();
      __builtin_amdgcn_sched_barrier(0);
    }
  }

  // ---- epilogue: combine quad partials ----
  float* Of = (float*)&smem[10240];    // [128 q][33] fp32 (pad-33)
  float* Df = (float*)&smem[18688];    // [128 q] fp32
  if (quad == 1) {
#pragma unroll
    for (int nq = 0; nq < 2; ++nq) {
      int qrow = wq * 32 + nq * 16 + ln;
#pragma unroll
      for (int md = 0; md < 2; ++md) {
        *(float4*)&Of[qrow * 33 + 16 * md + 4 * g] =
            make_float4(oacc[md][nq][0], oacc[md][nq][1],
                        oacc[md][nq][2], oacc[md][nq][3]);
      }
      Df[qrow] = oaccS[nq][0];
    }
  }
  __syncthreads();
  if (quad == 0) {
    ushort* otile = &smem[0];   // [128][40] overlays quad0 K (dead)
#pragma unroll
    for (int nq = 0; nq < 2; ++nq) {
      int qrow = wq * 32 + nq * 16 + ln;
      float rl = 1.f / (oaccS[nq][0] + Df[qrow]);
#pragma unroll
      for (int md = 0; md < 2; ++md) {
        float4 p = *(const float4*)&Of[qrow * 33 + 16 * md + 4 * g];
        uint2 pk = make_uint2(
            pkh((oacc[md][nq][0] + p.x) * rl, (oacc[md][nq][1] + p.y) * rl),
            pkh((oacc[md][nq][2] + p.z) * rl, (oacc[md][nq][3] + p.w) * rl));
        *(uint2*)&otile[qrow * 40 + 16 * md + 4 * g] = pk;
      }
    }
  }
  __syncthreads();
  if (t < 256) {
    int row = t >> 1, half = t & 1;
    uint4 v0 = *(const uint4*)&smem[row * 40 + half * 16];
    uint4 v1 = *(const uint4*)&smem[row * 40 + half * 16 + 8];
    ushort* dstp = ot + ((size_t)bh * L_ + q0b + row) * 32 + half * 16;
    *(uint4*)dstp = v0;
    *(uint4*)(dstp + 8) = v1;
  }
}

// ---------------------------------------------------------------------------
extern "C" void kernel_launch(void* const* d_in, const int* in_sizes, int n_in,
                              void* d_out, int out_size, void* d_ws, size_t ws_size,
                              hipStream_t stream) {
  const float* x      = (const float*)d_in[0];
  const float* gamma  = (const float*)d_in[1];
  const float* beta   = (const float*)d_in[2];
  const float* dw     = (const float*)d_in[3];
  const float* qkv_w  = (const float*)d_in[4];
  const float* qkv_b  = (const float*)d_in[5];
  const float* out_w  = (const float*)d_in[6];
  const float* out_b  = (const float*)d_in[7];
  float* out = (float*)d_out;

  char* ws = (char*)d_ws;
  ushort* ht   = (ushort*)(ws);                   // 4 MiB @0  (dead after qkv)
  ushort* qtb  = (ushort*)(ws + (16u << 20));     // 4 MiB @16
  ushort* ktb  = (ushort*)(ws + (20u << 20));     // 4 MiB @20
  ushort* vbb  = (ushort*)(ws + (24u << 20));     // 4 MiB @24
  ushort* otb  = (ushort*)(ws);                   // 4 MiB @0  (reuse ht)
  ushort* wq   = (ushort*)(ws + (28u << 20));     // 384 KiB @28M
  ushort* wo   = (ushort*)(ws + (28u << 20) + (512u << 10));  // 128 KiB

  gnw_kernel<<<384, 512, 0, stream>>>(x, gamma, beta, dw,
                                      (const float4*)qkv_w, (const float4*)out_w,
                                      (uint2*)wq, (uint2*)wo, ht);
  qkv_fused_kernel<<<dim3(8, 8, B_), 256, 0, stream>>>(ht, wq, qkv_b, qtb, ktb, vbb);
  attn_mfma_kernel<<<512, 512, 0, stream>>>(qtb, ktb, vbb, otb);
  outconv_kernel<<<dim3(8, 4, B_), 256, 0, stream>>>(otb, wo, out_b, x, out);
}

// Round 17
// 55.367 us; speedup vs baseline: 1.0694x; 1.0694x over previous
//
#include <hip/hip_runtime.h>
#include <hip/hip_bf16.h>

#define B_ 8
#define C_ 256
#define L_ 1024
#define NH_ 8
#define EPS_ 1e-5f

typedef __attribute__((ext_vector_type(8))) _Float16 half8;
typedef __attribute__((ext_vector_type(2))) __fp16 fp16x2;
typedef __attribute__((ext_vector_type(4))) float f32x4;

static __device__ inline ushort f2h(float f) {
  union { _Float16 h; ushort u; } c;
  c.h = (_Float16)f;
  return c.u;
}

// pack two fp32 -> fp16 pair via v_cvt_pkrtz_f16_f32 (compiler builtin --
// safe on TRANS-result inputs, unlike inline asm; rounds 9-11 lesson)
static __device__ inline uint pkh(float a, float b) {
  union { fp16x2 v; uint u; } c;
  c.v = __builtin_amdgcn_cvt_pkrtz(a, b);
  return c.u;
}

// ---------------------------------------------------------------------------
// Kernel A (512 threads): blocks 0-127: weight fp32->fp16 convert;
// blocks 128-383: GroupNorm + depthwise conv k=3. ht [B][32 cg][1024 l][8 c].
// ---------------------------------------------------------------------------
__global__ __launch_bounds__(512) void gnw_kernel(
    const float* __restrict__ x, const float* __restrict__ gamma,
    const float* __restrict__ beta, const float* __restrict__ dw,
    const float4* __restrict__ qw, const float4* __restrict__ ow,
    uint2* __restrict__ wq, uint2* __restrict__ wo_,
    ushort* __restrict__ ht) {
  __shared__ float hn[8 * L_];
  __shared__ float ws0[8], ws1[8];
  int t = threadIdx.x;
  if (blockIdx.x < 128) {
    int id = blockIdx.x * 512 + t;
    float4 v;
    uint2* dst;
    if (id < 49152) { v = qw[id]; dst = wq + id; }
    else { v = ow[id - 49152]; dst = wo_ + (id - 49152); }
    *dst = make_uint2(pkh(v.x, v.y), pkh(v.z, v.w));
    return;
  }
  int blk = blockIdx.x - 128;     // b*32 + g
  int b = blk >> 5, g = blk & 31;
  const size_t base = ((size_t)(b * C_ + g * 8)) * L_;

  float s = 0.f, ss = 0.f;
  float vals[16];
#pragma unroll
  for (int i = 0; i < 16; ++i) {
    int e = t + 512 * i;
    float v = x[base + e];
    vals[i] = v;
    s += v; ss += v * v;
  }
#pragma unroll
  for (int off = 32; off >= 1; off >>= 1) {
    s  += __shfl_xor(s, off);
    ss += __shfl_xor(ss, off);
  }
  int wave = t >> 6;
  if ((t & 63) == 0) { ws0[wave] = s; ws1[wave] = ss; }
  __syncthreads();
  s = 0.f; ss = 0.f;
#pragma unroll
  for (int i = 0; i < 8; ++i) { s += ws0[i]; ss += ws1[i]; }
  float mean = s * (1.f / 8192.f);
  float var = ss * (1.f / 8192.f) - mean * mean;
  float rstd = rsqrtf(var + EPS_);

#pragma unroll
  for (int i = 0; i < 16; ++i) {
    int e = t + 512 * i;
    int c = g * 8 + (i >> 1);
    float sc = gamma[c] * rstd;
    hn[e] = (vals[i] - mean) * sc + beta[c];
  }
  __syncthreads();
  float r[16];
#pragma unroll
  for (int i = 0; i < 16; ++i) {
    int e = t + 512 * i;
    int l = e & 1023;
    int c = g * 8 + (i >> 1);
    float w0 = dw[c * 3 + 0], w1 = dw[c * 3 + 1], w2 = dw[c * 3 + 2];
    float a = (l > 0) ? hn[e - 1] : 0.f;
    float m = hn[e];
    float z = (l < 1023) ? hn[e + 1] : 0.f;
    r[i] = w0 * a + w1 * m + w2 * z;
  }
#pragma unroll
  for (int li = 0; li < 2; ++li) {
    int l = t + 512 * li;
    uint4 pk;
    pk.x = pkh(r[0 + li],  r[2 + li]);
    pk.y = pkh(r[4 + li],  r[6 + li]);
    pk.z = pkh(r[8 + li],  r[10 + li]);
    pk.w = pkh(r[12 + li], r[14 + li]);
    *(uint4*)(ht + (((size_t)(b * 32 + g)) * L_ + l) * 8) = pk;
  }
}

// ---------------------------------------------------------------------------
// Kernel B: qkv pointwise conv via MFMA (fp16), fused repack epilogue.
// Input ht [B][32][1024][8]. Q PRE-SCALED by 1/sqrt(C)*log2(e).
// ---------------------------------------------------------------------------
__global__ __launch_bounds__(256) void qkv_fused_kernel(
    const ushort* __restrict__ Xt, const ushort* __restrict__ Wb,
    const float* __restrict__ bias, ushort* __restrict__ qt,
    ushort* __restrict__ kt, ushort* __restrict__ vb) {
  int bx = blockIdx.x, head = blockIdx.y, b = blockIdx.z;
  int bh = b * 8 + head;
  int t = threadIdx.x;
  int w = t >> 6, l = t & 63;
  int g = l >> 4, ln = l & 15;
  int wl = w >> 1, wo = w & 1;
  int lbase = bx * 128 + wl * 64;

  const ushort* xb = Xt + (size_t)b * (32 * L_ * 8);
  const ushort* wp = Wb + (size_t)(head * 96 + wo * 48) * 256;

  f32x4 acc[4][3];
#pragma unroll
  for (int ml = 0; ml < 4; ++ml)
#pragma unroll
    for (int nn = 0; nn < 3; ++nn) acc[ml][nn] = (f32x4){0.f, 0.f, 0.f, 0.f};

  for (int c0 = 0; c0 < 256; c0 += 32) {
    half8 af[4], bf[3];
#pragma unroll
    for (int ml = 0; ml < 4; ++ml)
      af[ml] = *(const half8*)(xb +
          (((size_t)((c0 >> 3) + g)) * L_ + lbase + 16 * ml + ln) * 8);
#pragma unroll
    for (int nn = 0; nn < 3; ++nn)
      bf[nn] = *(const half8*)(wp + (size_t)(16 * nn + ln) * 256 + c0 + 8 * g);
#pragma unroll
    for (int ml = 0; ml < 4; ++ml)
#pragma unroll
      for (int nn = 0; nn < 3; ++nn)
        acc[ml][nn] = __builtin_amdgcn_mfma_f32_16x16x32_f16(af[ml], bf[nn], acc[ml][nn], 0, 0, 0);
  }

  // bias
#pragma unroll
  for (int nn = 0; nn < 3; ++nn) {
    float bs = bias[head * 96 + wo * 48 + 16 * nn + ln];
#pragma unroll
    for (int ml = 0; ml < 4; ++ml)
#pragma unroll
      for (int r = 0; r < 4; ++r) acc[ml][nn][r] += bs;
  }

  __shared__ ushort tr[5120];
  const float QSC = 0.0625f * 1.44269504f;   // 1/sqrt(256) * log2(e)

  // rounds 0 (q, scaled), 1 (k): transpose to [l][d] (pad 40), write [bh][l][32]
  for (int rk = 0; rk < 2; ++rk) {
    float sc = rk ? 1.f : QSC;
    __syncthreads();
#pragma unroll
    for (int nn = 0; nn < 3; ++nn) {
      int ocl0 = wo * 48 + 16 * nn;
      if (ocl0 >= rk * 32 && ocl0 < rk * 32 + 32) {
        int d = ocl0 - rk * 32 + ln;
#pragma unroll
        for (int ml = 0; ml < 4; ++ml) {
          int lrow = wl * 64 + 16 * ml + 4 * g;
#pragma unroll
          for (int r = 0; r < 4; ++r)
            tr[(lrow + r) * 40 + d] = f2h(acc[ml][nn][r] * sc);
        }
      }
    }
    __syncthreads();
    {
      int row = t >> 1, half = t & 1;
      uint4 v0 = *(const uint4*)&tr[row * 40 + half * 16];
      uint4 v1 = *(const uint4*)&tr[row * 40 + half * 16 + 8];
      ushort* dst = (rk ? kt : qt) +
                    ((size_t)bh * L_ + bx * 128 + row) * 32 + half * 16;
      *(uint4*)dst = v0;
      *(uint4*)(dst + 8) = v1;
    }
  }

  // round 2 (v): [d][l] (pad 136), PI-permute on global write
  __syncthreads();
  if (wo == 1) {
#pragma unroll
    for (int nn = 1; nn < 3; ++nn) {
      int d = 16 * (nn - 1) + ln;
#pragma unroll
      for (int ml = 0; ml < 4; ++ml) {
        int lc = wl * 64 + 16 * ml + 4 * g;
        *(uint2*)&tr[d * 136 + lc] =
            make_uint2(pkh(acc[ml][nn][0], acc[ml][nn][1]),
                       pkh(acc[ml][nn][2], acc[ml][nn][3]));
      }
    }
  }
  __syncthreads();
  {
    int d = t >> 3, s0 = t & 7;
    ushort* vdst = vb + ((size_t)bh * 32 + d) * L_ + bx * 128;
#pragma unroll
    for (int c = 0; c < 2; ++c) {
      int ch = s0 + 8 * c;
      int jj = ch >> 2, gg = ch & 3;
      uint2 lo = *(const uint2*)&tr[d * 136 + 32 * jj + 4 * gg];
      uint2 hi = *(const uint2*)&tr[d * 136 + 32 * jj + 16 + 4 * gg];
      *(uint4*)(vdst + 32 * jj + 8 * gg) = make_uint4(lo.x, lo.y, hi.x, hi.y);
    }
  }
}

// ---------------------------------------------------------------------------
// Kernel D: out pointwise conv via MFMA (fp16) + residual. Input ot
// [bh][1024][32]. Block = 128 l x 64 oc. grid (8, 4, B) = 256.
// ---------------------------------------------------------------------------
__global__ __launch_bounds__(256) void outconv_kernel(
    const ushort* __restrict__ Xt, const ushort* __restrict__ Wb,
    const float* __restrict__ bias, const float* __restrict__ resid,
    float* __restrict__ out) {
  int b = blockIdx.z;
  int t = threadIdx.x;
  int w = t >> 6, l = t & 63;
  int g = l >> 4, ln = l & 15;
  int lbase = blockIdx.x * 128;
  int ocblk = blockIdx.y * 64;
  int ocbase = ocblk + w * 16;

  const ushort* xb = Xt + (size_t)b * (8 * L_ * 32);
  const ushort* wp = Wb + (size_t)ocbase * 256;

  f32x4 acc[8];
#pragma unroll
  for (int ml = 0; ml < 8; ++ml) acc[ml] = (f32x4){0.f, 0.f, 0.f, 0.f};

  for (int c0 = 0; c0 < 256; c0 += 32) {
    half8 af[8];
#pragma unroll
    for (int ml = 0; ml < 8; ++ml)
      af[ml] = *(const half8*)(xb +
          ((size_t)(c0 >> 5) * L_ + lbase + 16 * ml + ln) * 32 + 8 * g);
    half8 bf = *(const half8*)(wp + (size_t)ln * 256 + c0 + 8 * g);
#pragma unroll
    for (int ml = 0; ml < 8; ++ml)
      acc[ml] = __builtin_amdgcn_mfma_f32_16x16x32_f16(af[ml], bf, acc[ml], 0, 0, 0);
  }

  __shared__ float tile[64][132];   // 33 KB
  float bs = bias[ocbase + ln];
#pragma unroll
  for (int ml = 0; ml < 8; ++ml) {
    int ll = 16 * ml + 4 * g;
    float4 v = make_float4(acc[ml][0] + bs, acc[ml][1] + bs,
                           acc[ml][2] + bs, acc[ml][3] + bs);
    *(float4*)&tile[w * 16 + ln][ll] = v;
  }
  __syncthreads();
  {
    int ocl = t >> 2, lq = t & 3;           // 64 oc x 4 l-chunks of 32
    const float* src = &tile[ocl][lq * 32];
    size_t ob = ((size_t)b * 256 + ocblk + ocl) * L_ + lbase + lq * 32;
#pragma unroll
    for (int i = 0; i < 8; ++i) {
      float4 v = *(const float4*)(src + 4 * i);
      float4 rd = *(const float4*)(resid + ob + 4 * i);
      v.x += rd.x; v.y += rd.y; v.z += rd.z; v.w += rd.w;
      *(float4*)(out + ob + 4 * i) = v;
    }
  }
}

// ---------------------------------------------------------------------------
// Kernel C: MFMA flash attention (round-15 structure, reverted from kv-split),
// fp16 pipeline, no max-subtraction, exp via v_exp_f32, pack via cvt_pkrtz.
// dbuf K+V LDS staging, padded layouts, otile overlays K0. 256 thr, grid 512.
// ONLY delta vs round 15: s_setprio(1/0) around the PV MFMA cluster (T5).
// ---------------------------------------------------------------------------
__global__ __launch_bounds__(256) void attn_mfma_kernel(
    const ushort* __restrict__ qt, const ushort* __restrict__ kt,
    const ushort* __restrict__ vb, ushort* __restrict__ ot) {
  const int id = blockIdx.x;
  const int bh = ((id & 7) << 3) | (id >> 6);
  const int qtile = (id >> 3) & 7;
  const int t = threadIdx.x;
  const int w = t >> 6, l = t & 63;
  const int g = l >> 4, ln = l & 15;
  const int q0b = qtile * 128;
  const int q0 = q0b + w * 32;

  // smem (ushorts): K0 @0 (5120), K1 @5120, V0 @10240 (4352), V1 @14592.
  // otile [128][40] = 5120 overlays K0 (dead in tt=7 / epilogue).
  __shared__ __align__(16) ushort smem[18944];   // 37,888 B

  const ushort* qbase = qt + (size_t)bh * (L_ * 32);
  const ushort* kbase = kt + (size_t)bh * (L_ * 32);
  const ushort* vbase = vb + (size_t)bh * (32 * L_);

  // staging geometry
  const int krow = t >> 1, khalf = t & 1;
  const ushort* kg = kbase + krow * 32 + khalf * 16;
  const int kwo = krow * 40 + khalf * 16;
  const int vrow = t >> 3, vc = (t & 7) * 16;
  const ushort* vg = vbase + (size_t)vrow * L_ + vc;
  const int vwo = vrow * 136 + vc;

  const f32x4 z4 = {0.f, 0.f, 0.f, 0.f};
  half8 bq[2];
  bq[0] = *(const half8*)(qbase + (size_t)(q0 + ln) * 32 + g * 8);
  bq[1] = *(const half8*)(qbase + (size_t)(q0 + 16 + ln) * 32 + g * 8);

  union { ushort s[8]; half8 v; } onesu;
#pragma unroll
  for (int i = 0; i < 8; ++i) onesu.s[i] = 0x3C00;  // fp16 1.0
  const half8 ones = onesu.v;

  f32x4 oacc[2][2];  // [md][nq]
  oacc[0][0] = z4; oacc[0][1] = z4; oacc[1][0] = z4; oacc[1][1] = z4;
  f32x4 oaccS[2] = {z4, z4};

  // prologue: stage tile 0
  uint4 ka0, ka1, va0, va1;
  ka0 = *(const uint4*)kg;       ka1 = *(const uint4*)(kg + 8);
  va0 = *(const uint4*)vg;       va1 = *(const uint4*)(vg + 8);
  __builtin_amdgcn_sched_barrier(0);
  *(uint4*)&smem[kwo] = ka0;             *(uint4*)&smem[kwo + 8] = ka1;
  *(uint4*)&smem[10240 + vwo] = va0;     *(uint4*)&smem[10240 + vwo + 8] = va1;
  asm volatile("s_waitcnt lgkmcnt(0)" ::: "memory");
  __builtin_amdgcn_s_barrier();
  __builtin_amdgcn_sched_barrier(0);

  for (int tt = 0; tt < 8; ++tt) {
    const int cur = tt & 1;
    if (tt < 7) {
      ka0 = *(const uint4*)(kg + (tt + 1) * 4096);
      ka1 = *(const uint4*)(kg + (tt + 1) * 4096 + 8);
      va0 = *(const uint4*)(vg + (tt + 1) * 128);
      va1 = *(const uint4*)(vg + (tt + 1) * 128 + 8);
    }
    __builtin_amdgcn_sched_barrier(0);

    const ushort* Kc = &smem[cur * 5120];
    const ushort* Vc = &smem[10240 + cur * 4352];

    // QK^T  (S already in log2-units thanks to Q pre-scale)
    f32x4 sacc[8][2];
#pragma unroll
    for (int mk = 0; mk < 8; ++mk) {
      half8 ak = *(const half8*)(Kc + (16 * mk + ln) * 40 + g * 8);
      sacc[mk][0] = __builtin_amdgcn_mfma_f32_16x16x32_f16(ak, bq[0], z4, 0, 0, 0);
      sacc[mk][1] = __builtin_amdgcn_mfma_f32_16x16x32_f16(ak, bq[1], z4, 0, 0, 0);
    }

    // exp via v_exp_f32; pack pairs via cvt_pkrtz (compiler builtin -- safe
    // TRANS consumer, 1 op per 2 elems)
    uint upk[2][8][2];
#pragma unroll
    for (int nq = 0; nq < 2; ++nq) {
#pragma unroll
      for (int mk = 0; mk < 8; ++mk) {
        float e0 = __builtin_amdgcn_exp2f(sacc[mk][nq][0]);
        float e1 = __builtin_amdgcn_exp2f(sacc[mk][nq][1]);
        float e2 = __builtin_amdgcn_exp2f(sacc[mk][nq][2]);
        float e3 = __builtin_amdgcn_exp2f(sacc[mk][nq][3]);
        upk[nq][mk][0] = pkh(e0, e1);
        upk[nq][mk][1] = pkh(e2, e3);
      }
    }

    // PV + denominator (T5: boost wave priority through the MFMA cluster)
    __builtin_amdgcn_s_setprio(1);
#pragma unroll
    for (int ks = 0; ks < 4; ++ks) {
      union { uint u[4]; half8 v; } pb0, pb1;
      pb0.u[0] = upk[0][2 * ks][0]; pb0.u[1] = upk[0][2 * ks][1];
      pb0.u[2] = upk[0][2 * ks + 1][0]; pb0.u[3] = upk[0][2 * ks + 1][1];
      pb1.u[0] = upk[1][2 * ks][0]; pb1.u[1] = upk[1][2 * ks][1];
      pb1.u[2] = upk[1][2 * ks + 1][0]; pb1.u[3] = upk[1][2 * ks + 1][1];
      oaccS[0] = __builtin_amdgcn_mfma_f32_16x16x32_f16(ones, pb0.v, oaccS[0], 0, 0, 0);
      oaccS[1] = __builtin_amdgcn_mfma_f32_16x16x32_f16(ones, pb1.v, oaccS[1], 0, 0, 0);
#pragma unroll
      for (int md = 0; md < 2; ++md) {
        half8 av = *(const half8*)(Vc + (16 * md + ln) * 136 + 32 * ks + 8 * g);
        oacc[md][0] = __builtin_amdgcn_mfma_f32_16x16x32_f16(av, pb0.v, oacc[md][0], 0, 0, 0);
        oacc[md][1] = __builtin_amdgcn_mfma_f32_16x16x32_f16(av, pb1.v, oacc[md][1], 0, 0, 0);
      }
    }
    __builtin_amdgcn_s_setprio(0);

    __builtin_amdgcn_sched_barrier(0);
    if (tt < 7) {
      const int nxt = cur ^ 1;
      *(uint4*)&smem[nxt * 5120 + kwo] = ka0;
      *(uint4*)&smem[nxt * 5120 + kwo + 8] = ka1;
      *(uint4*)&smem[10240 + nxt * 4352 + vwo] = va0;
      *(uint4*)&smem[10240 + nxt * 4352 + vwo + 8] = va1;
      asm volatile("s_waitcnt lgkmcnt(0)" ::: "memory");
      __builtin_amdgcn_s_barrier();
      __builtin_amdgcn_sched_barrier(0);
    }
  }

  // epilogue: normalize, LDS transpose (otile overlays K0), write ot[bh][l][32]
  ushort* otile = &smem[0];   // [128][40]
  float rl0 = 1.f / oaccS[0][0];
  float rl1 = 1.f / oaccS[1][0];
#pragma unroll
  for (int md = 0; md < 2; ++md) {
    uint2 p0 = make_uint2(pkh(oacc[md][0][0] * rl0, oacc[md][0][1] * rl0),
                          pkh(oacc[md][0][2] * rl0, oacc[md][0][3] * rl0));
    uint2 p1 = make_uint2(pkh(oacc[md][1][0] * rl1, oacc[md][1][1] * rl1),
                          pkh(oacc[md][1][2] * rl1, oacc[md][1][3] * rl1));
    *(uint2*)&otile[(w * 32 + ln) * 40 + 16 * md + 4 * g] = p0;
    *(uint2*)&otile[(w * 32 + 16 + ln) * 40 + 16 * md + 4 * g] = p1;
  }
  __syncthreads();
  {
    int row = t >> 1, half = t & 1;
    uint4 v0 = *(const uint4*)&otile[row * 40 + half * 16];
    uint4 v1 = *(const uint4*)&otile[row * 40 + half * 16 + 8];
    ushort* dstp = ot + ((size_t)bh * L_ + q0b + row) * 32 + half * 16;
    *(uint4*)dstp = v0;
    *(uint4*)(dstp + 8) = v1;
  }
}

// ---------------------------------------------------------------------------
extern "C" void kernel_launch(void* const* d_in, const int* in_sizes, int n_in,
                              void* d_out, int out_size, void* d_ws, size_t ws_size,
                              hipStream_t stream) {
  const float* x      = (const float*)d_in[0];
  const float* gamma  = (const float*)d_in[1];
  const float* beta   = (const float*)d_in[2];
  const float* dw     = (const float*)d_in[3];
  const float* qkv_w  = (const float*)d_in[4];
  const float* qkv_b  = (const float*)d_in[5];
  const float* out_w  = (const float*)d_in[6];
  const float* out_b  = (const float*)d_in[7];
  float* out = (float*)d_out;

  char* ws = (char*)d_ws;
  ushort* ht   = (ushort*)(ws);                   // 4 MiB @0  (dead after qkv)
  ushort* qtb  = (ushort*)(ws + (16u << 20));     // 4 MiB @16
  ushort* ktb  = (ushort*)(ws + (20u << 20));     // 4 MiB @20
  ushort* vbb  = (ushort*)(ws + (24u << 20));     // 4 MiB @24
  ushort* otb  = (ushort*)(ws);                   // 4 MiB @0  (reuse ht)
  ushort* wq   = (ushort*)(ws + (28u << 20));     // 384 KiB @28M
  ushort* wo   = (ushort*)(ws + (28u << 20) + (512u << 10));  // 128 KiB

  gnw_kernel<<<384, 512, 0, stream>>>(x, gamma, beta, dw,
                                      (const float4*)qkv_w, (const float4*)out_w,
                                      (uint2*)wq, (uint2*)wo, ht);
  qkv_fused_kernel<<<dim3(8, 8, B_), 256, 0, stream>>>(ht, wq, qkv_b, qtb, ktb, vbb);
  attn_mfma_kernel<<<512, 256, 0, stream>>>(qtb, ktb, vbb, otb);
  outconv_kernel<<<dim3(8, 4, B_), 256, 0, stream>>>(otb, wo, out_b, x, out);
}

// Round 18
// 53.293 us; speedup vs baseline: 1.1110x; 1.0389x over previous
//
#include <hip/hip_runtime.h>
#include <hip/hip_bf16.h>

#define B_ 8
#define C_ 256
#define L_ 1024
#define NH_ 8
#define EPS_ 1e-5f

typedef __attribute__((ext_vector_type(8))) _Float16 half8;
typedef __attribute__((ext_vector_type(2))) __fp16 fp16x2;
typedef __attribute__((ext_vector_type(4))) float f32x4;

static __device__ inline ushort f2h(float f) {
  union { _Float16 h; ushort u; } c;
  c.h = (_Float16)f;
  return c.u;
}

// pack two fp32 -> fp16 pair via v_cvt_pkrtz_f16_f32 (compiler builtin --
// safe on TRANS-result inputs, unlike inline asm; rounds 9-11 lesson)
static __device__ inline uint pkh(float a, float b) {
  union { fp16x2 v; uint u; } c;
  c.v = __builtin_amdgcn_cvt_pkrtz(a, b);
  return c.u;
}

// ---------------------------------------------------------------------------
// Kernel A (512 threads): blocks 0-127: weight fp32->fp16 convert;
// blocks 128-383: GroupNorm + depthwise conv k=3. ht [B][32 cg][1024 l][8 c].
// ---------------------------------------------------------------------------
__global__ __launch_bounds__(512) void gnw_kernel(
    const float* __restrict__ x, const float* __restrict__ gamma,
    const float* __restrict__ beta, const float* __restrict__ dw,
    const float4* __restrict__ qw, const float4* __restrict__ ow,
    uint2* __restrict__ wq, uint2* __restrict__ wo_,
    ushort* __restrict__ ht) {
  __shared__ float hn[8 * L_];
  __shared__ float ws0[8], ws1[8];
  int t = threadIdx.x;
  if (blockIdx.x < 128) {
    int id = blockIdx.x * 512 + t;
    float4 v;
    uint2* dst;
    if (id < 49152) { v = qw[id]; dst = wq + id; }
    else { v = ow[id - 49152]; dst = wo_ + (id - 49152); }
    *dst = make_uint2(pkh(v.x, v.y), pkh(v.z, v.w));
    return;
  }
  int blk = blockIdx.x - 128;     // b*32 + g
  int b = blk >> 5, g = blk & 31;
  const size_t base = ((size_t)(b * C_ + g * 8)) * L_;

  float s = 0.f, ss = 0.f;
  float vals[16];
#pragma unroll
  for (int i = 0; i < 16; ++i) {
    int e = t + 512 * i;
    float v = x[base + e];
    vals[i] = v;
    s += v; ss += v * v;
  }
#pragma unroll
  for (int off = 32; off >= 1; off >>= 1) {
    s  += __shfl_xor(s, off);
    ss += __shfl_xor(ss, off);
  }
  int wave = t >> 6;
  if ((t & 63) == 0) { ws0[wave] = s; ws1[wave] = ss; }
  __syncthreads();
  s = 0.f; ss = 0.f;
#pragma unroll
  for (int i = 0; i < 8; ++i) { s += ws0[i]; ss += ws1[i]; }
  float mean = s * (1.f / 8192.f);
  float var = ss * (1.f / 8192.f) - mean * mean;
  float rstd = rsqrtf(var + EPS_);

#pragma unroll
  for (int i = 0; i < 16; ++i) {
    int e = t + 512 * i;
    int c = g * 8 + (i >> 1);
    float sc = gamma[c] * rstd;
    hn[e] = (vals[i] - mean) * sc + beta[c];
  }
  __syncthreads();
  float r[16];
#pragma unroll
  for (int i = 0; i < 16; ++i) {
    int e = t + 512 * i;
    int l = e & 1023;
    int c = g * 8 + (i >> 1);
    float w0 = dw[c * 3 + 0], w1 = dw[c * 3 + 1], w2 = dw[c * 3 + 2];
    float a = (l > 0) ? hn[e - 1] : 0.f;
    float m = hn[e];
    float z = (l < 1023) ? hn[e + 1] : 0.f;
    r[i] = w0 * a + w1 * m + w2 * z;
  }
#pragma unroll
  for (int li = 0; li < 2; ++li) {
    int l = t + 512 * li;
    uint4 pk;
    pk.x = pkh(r[0 + li],  r[2 + li]);
    pk.y = pkh(r[4 + li],  r[6 + li]);
    pk.z = pkh(r[8 + li],  r[10 + li]);
    pk.w = pkh(r[12 + li], r[14 + li]);
    *(uint4*)(ht + (((size_t)(b * 32 + g)) * L_ + l) * 8) = pk;
  }
}

// ---------------------------------------------------------------------------
// Kernel B: qkv pointwise conv via MFMA (fp16), fused repack epilogue.
// Input ht [B][32][1024][8]. Q PRE-SCALED by 1/sqrt(C)*log2(e).
// ---------------------------------------------------------------------------
__global__ __launch_bounds__(256) void qkv_fused_kernel(
    const ushort* __restrict__ Xt, const ushort* __restrict__ Wb,
    const float* __restrict__ bias, ushort* __restrict__ qt,
    ushort* __restrict__ kt, ushort* __restrict__ vb) {
  int bx = blockIdx.x, head = blockIdx.y, b = blockIdx.z;
  int bh = b * 8 + head;
  int t = threadIdx.x;
  int w = t >> 6, l = t & 63;
  int g = l >> 4, ln = l & 15;
  int wl = w >> 1, wo = w & 1;
  int lbase = bx * 128 + wl * 64;

  const ushort* xb = Xt + (size_t)b * (32 * L_ * 8);
  const ushort* wp = Wb + (size_t)(head * 96 + wo * 48) * 256;

  f32x4 acc[4][3];
#pragma unroll
  for (int ml = 0; ml < 4; ++ml)
#pragma unroll
    for (int nn = 0; nn < 3; ++nn) acc[ml][nn] = (f32x4){0.f, 0.f, 0.f, 0.f};

  for (int c0 = 0; c0 < 256; c0 += 32) {
    half8 af[4], bf[3];
#pragma unroll
    for (int ml = 0; ml < 4; ++ml)
      af[ml] = *(const half8*)(xb +
          (((size_t)((c0 >> 3) + g)) * L_ + lbase + 16 * ml + ln) * 8);
#pragma unroll
    for (int nn = 0; nn < 3; ++nn)
      bf[nn] = *(const half8*)(wp + (size_t)(16 * nn + ln) * 256 + c0 + 8 * g);
#pragma unroll
    for (int ml = 0; ml < 4; ++ml)
#pragma unroll
      for (int nn = 0; nn < 3; ++nn)
        acc[ml][nn] = __builtin_amdgcn_mfma_f32_16x16x32_f16(af[ml], bf[nn], acc[ml][nn], 0, 0, 0);
  }

  // bias
#pragma unroll
  for (int nn = 0; nn < 3; ++nn) {
    float bs = bias[head * 96 + wo * 48 + 16 * nn + ln];
#pragma unroll
    for (int ml = 0; ml < 4; ++ml)
#pragma unroll
      for (int r = 0; r < 4; ++r) acc[ml][nn][r] += bs;
  }

  __shared__ ushort tr[5120];
  const float QSC = 0.0625f * 1.44269504f;   // 1/sqrt(256) * log2(e)

  // rounds 0 (q, scaled), 1 (k): transpose to [l][d] (pad 40), write [bh][l][32]
  for (int rk = 0; rk < 2; ++rk) {
    float sc = rk ? 1.f : QSC;
    __syncthreads();
#pragma unroll
    for (int nn = 0; nn < 3; ++nn) {
      int ocl0 = wo * 48 + 16 * nn;
      if (ocl0 >= rk * 32 && ocl0 < rk * 32 + 32) {
        int d = ocl0 - rk * 32 + ln;
#pragma unroll
        for (int ml = 0; ml < 4; ++ml) {
          int lrow = wl * 64 + 16 * ml + 4 * g;
#pragma unroll
          for (int r = 0; r < 4; ++r)
            tr[(lrow + r) * 40 + d] = f2h(acc[ml][nn][r] * sc);
        }
      }
    }
    __syncthreads();
    {
      int row = t >> 1, half = t & 1;
      uint4 v0 = *(const uint4*)&tr[row * 40 + half * 16];
      uint4 v1 = *(const uint4*)&tr[row * 40 + half * 16 + 8];
      ushort* dst = (rk ? kt : qt) +
                    ((size_t)bh * L_ + bx * 128 + row) * 32 + half * 16;
      *(uint4*)dst = v0;
      *(uint4*)(dst + 8) = v1;
    }
  }

  // round 2 (v): [d][l] (pad 136), PI-permute on global write
  __syncthreads();
  if (wo == 1) {
#pragma unroll
    for (int nn = 1; nn < 3; ++nn) {
      int d = 16 * (nn - 1) + ln;
#pragma unroll
      for (int ml = 0; ml < 4; ++ml) {
        int lc = wl * 64 + 16 * ml + 4 * g;
        *(uint2*)&tr[d * 136 + lc] =
            make_uint2(pkh(acc[ml][nn][0], acc[ml][nn][1]),
                       pkh(acc[ml][nn][2], acc[ml][nn][3]));
      }
    }
  }
  __syncthreads();
  {
    int d = t >> 3, s0 = t & 7;
    ushort* vdst = vb + ((size_t)bh * 32 + d) * L_ + bx * 128;
#pragma unroll
    for (int c = 0; c < 2; ++c) {
      int ch = s0 + 8 * c;
      int jj = ch >> 2, gg = ch & 3;
      uint2 lo = *(const uint2*)&tr[d * 136 + 32 * jj + 4 * gg];
      uint2 hi = *(const uint2*)&tr[d * 136 + 32 * jj + 16 + 4 * gg];
      *(uint4*)(vdst + 32 * jj + 8 * gg) = make_uint4(lo.x, lo.y, hi.x, hi.y);
    }
  }
}

// ---------------------------------------------------------------------------
// Kernel D: out pointwise conv via MFMA (fp16) + residual. Input ot
// [bh][1024][32]. Block = 128 l x 64 oc. grid (8, 4, B) = 256.
// ---------------------------------------------------------------------------
__global__ __launch_bounds__(256) void outconv_kernel(
    const ushort* __restrict__ Xt, const ushort* __restrict__ Wb,
    const float* __restrict__ bias, const float* __restrict__ resid,
    float* __restrict__ out) {
  int b = blockIdx.z;
  int t = threadIdx.x;
  int w = t >> 6, l = t & 63;
  int g = l >> 4, ln = l & 15;
  int lbase = blockIdx.x * 128;
  int ocblk = blockIdx.y * 64;
  int ocbase = ocblk + w * 16;

  const ushort* xb = Xt + (size_t)b * (8 * L_ * 32);
  const ushort* wp = Wb + (size_t)ocbase * 256;

  f32x4 acc[8];
#pragma unroll
  for (int ml = 0; ml < 8; ++ml) acc[ml] = (f32x4){0.f, 0.f, 0.f, 0.f};

  for (int c0 = 0; c0 < 256; c0 += 32) {
    half8 af[8];
#pragma unroll
    for (int ml = 0; ml < 8; ++ml)
      af[ml] = *(const half8*)(xb +
          ((size_t)(c0 >> 5) * L_ + lbase + 16 * ml + ln) * 32 + 8 * g);
    half8 bf = *(const half8*)(wp + (size_t)ln * 256 + c0 + 8 * g);
#pragma unroll
    for (int ml = 0; ml < 8; ++ml)
      acc[ml] = __builtin_amdgcn_mfma_f32_16x16x32_f16(af[ml], bf, acc[ml], 0, 0, 0);
  }

  __shared__ float tile[64][132];   // 33 KB
  float bs = bias[ocbase + ln];
#pragma unroll
  for (int ml = 0; ml < 8; ++ml) {
    int ll = 16 * ml + 4 * g;
    float4 v = make_float4(acc[ml][0] + bs, acc[ml][1] + bs,
                           acc[ml][2] + bs, acc[ml][3] + bs);
    *(float4*)&tile[w * 16 + ln][ll] = v;
  }
  __syncthreads();
  {
    int ocl = t >> 2, lq = t & 3;           // 64 oc x 4 l-chunks of 32
    const float* src = &tile[ocl][lq * 32];
    size_t ob = ((size_t)b * 256 + ocblk + ocl) * L_ + lbase + lq * 32;
#pragma unroll
    for (int i = 0; i < 8; ++i) {
      float4 v = *(const float4*)(src + 4 * i);
      float4 rd = *(const float4*)(resid + ob + 4 * i);
      v.x += rd.x; v.y += rd.y; v.z += rd.z; v.w += rd.w;
      *(float4*)(out + ob + 4 * i) = v;
    }
  }
}

// ---------------------------------------------------------------------------
// Kernel C: MFMA flash attention, 8 waves x 16q = 128q per block (512 thr).
// Same grid (512), same staging bytes, same barriers as round-15; per-wave
// serial work halved, waves/CU doubled (16 = 4/SIMD). No setprio (T5 null).
// fp16 pipeline, no max-subtraction, exp via v_exp_f32, pack via cvt_pkrtz.
// ---------------------------------------------------------------------------
__global__ __launch_bounds__(512) void attn_mfma_kernel(
    const ushort* __restrict__ qt, const ushort* __restrict__ kt,
    const ushort* __restrict__ vb, ushort* __restrict__ ot) {
  const int id = blockIdx.x;
  const int bh = ((id & 7) << 3) | (id >> 6);
  const int qtile = (id >> 3) & 7;
  const int t = threadIdx.x;
  const int w = t >> 6, l = t & 63;
  const int g = l >> 4, ln = l & 15;
  const int q0b = qtile * 128;
  const int q0 = q0b + w * 16;

  // smem (ushorts): K0 @0 (5120), K1 @5120, V0 @10240 (4352), V1 @14592.
  // otile [128][40] = 5120 overlays K0 (dead in tt=7 / epilogue).
  __shared__ __align__(16) ushort smem[18944];   // 37,888 B

  const ushort* qbase = qt + (size_t)bh * (L_ * 32);
  const ushort* kbase = kt + (size_t)bh * (L_ * 32);
  const ushort* vbase = vb + (size_t)bh * (32 * L_);

  // staging geometry (512 threads, 1 x 16B each for K and V per tile)
  const int krow = t >> 2, kchunk = t & 3;           // K: 128 rows x 4 chunks
  const ushort* kg = kbase + krow * 32 + kchunk * 8;
  const int kwo = krow * 40 + kchunk * 8;
  const int vrow = t >> 4, vchunk = t & 15;          // V: 32 rows x 16 chunks
  const ushort* vg = vbase + (size_t)vrow * L_ + vchunk * 8;
  const int vwo = vrow * 136 + vchunk * 8;

  const f32x4 z4 = {0.f, 0.f, 0.f, 0.f};
  const half8 bq = *(const half8*)(qbase + (size_t)(q0 + ln) * 32 + g * 8);

  union { ushort s[8]; half8 v; } onesu;
#pragma unroll
  for (int i = 0; i < 8; ++i) onesu.s[i] = 0x3C00;  // fp16 1.0
  const half8 ones = onesu.v;

  f32x4 oacc[2] = {z4, z4};   // [md]
  f32x4 oaccS = z4;

  // prologue: stage tile 0
  uint4 ka0, va0;
  ka0 = *(const uint4*)kg;
  va0 = *(const uint4*)vg;
  __builtin_amdgcn_sched_barrier(0);
  *(uint4*)&smem[kwo] = ka0;
  *(uint4*)&smem[10240 + vwo] = va0;
  asm volatile("s_waitcnt lgkmcnt(0)" ::: "memory");
  __builtin_amdgcn_s_barrier();
  __builtin_amdgcn_sched_barrier(0);

  for (int tt = 0; tt < 8; ++tt) {
    const int cur = tt & 1;
    if (tt < 7) {
      ka0 = *(const uint4*)(kg + (tt + 1) * 4096);
      va0 = *(const uint4*)(vg + (tt + 1) * 128);
    }
    __builtin_amdgcn_sched_barrier(0);

    const ushort* Kc = &smem[cur * 5120];
    const ushort* Vc = &smem[10240 + cur * 4352];

    // QK^T  (S already in log2-units thanks to Q pre-scale)
    f32x4 sacc[8];
#pragma unroll
    for (int mk = 0; mk < 8; ++mk) {
      half8 ak = *(const half8*)(Kc + (16 * mk + ln) * 40 + g * 8);
      sacc[mk] = __builtin_amdgcn_mfma_f32_16x16x32_f16(ak, bq, z4, 0, 0, 0);
    }

    // exp via v_exp_f32; pack pairs via cvt_pkrtz (compiler builtin -- safe
    // TRANS consumer)
    uint upk[8][2];
#pragma unroll
    for (int mk = 0; mk < 8; ++mk) {
      float e0 = __builtin_amdgcn_exp2f(sacc[mk][0]);
      float e1 = __builtin_amdgcn_exp2f(sacc[mk][1]);
      float e2 = __builtin_amdgcn_exp2f(sacc[mk][2]);
      float e3 = __builtin_amdgcn_exp2f(sacc[mk][3]);
      upk[mk][0] = pkh(e0, e1);
      upk[mk][1] = pkh(e2, e3);
    }

    // PV + denominator
#pragma unroll
    for (int ks = 0; ks < 4; ++ks) {
      union { uint u[4]; half8 v; } pb;
      pb.u[0] = upk[2 * ks][0];     pb.u[1] = upk[2 * ks][1];
      pb.u[2] = upk[2 * ks + 1][0]; pb.u[3] = upk[2 * ks + 1][1];
      oaccS = __builtin_amdgcn_mfma_f32_16x16x32_f16(ones, pb.v, oaccS, 0, 0, 0);
#pragma unroll
      for (int md = 0; md < 2; ++md) {
        half8 av = *(const half8*)(Vc + (16 * md + ln) * 136 + 32 * ks + 8 * g);
        oacc[md] = __builtin_amdgcn_mfma_f32_16x16x32_f16(av, pb.v, oacc[md], 0, 0, 0);
      }
    }

    __builtin_amdgcn_sched_barrier(0);
    if (tt < 7) {
      const int nxt = cur ^ 1;
      *(uint4*)&smem[nxt * 5120 + kwo] = ka0;
      *(uint4*)&smem[10240 + nxt * 4352 + vwo] = va0;
      asm volatile("s_waitcnt lgkmcnt(0)" ::: "memory");
      __builtin_amdgcn_s_barrier();
      __builtin_amdgcn_sched_barrier(0);
    }
  }

  // epilogue: normalize, LDS transpose (otile overlays K0), write ot[bh][l][32]
  ushort* otile = &smem[0];   // [128][40]
  float rl = 1.f / oaccS[0];
  int q_loc = w * 16 + ln;
#pragma unroll
  for (int md = 0; md < 2; ++md) {
    uint2 pk = make_uint2(pkh(oacc[md][0] * rl, oacc[md][1] * rl),
                          pkh(oacc[md][2] * rl, oacc[md][3] * rl));
    *(uint2*)&otile[q_loc * 40 + 16 * md + 4 * g] = pk;
  }
  __syncthreads();
  {
    int row = t >> 2, qu = t & 3;
    uint4 v = *(const uint4*)&otile[row * 40 + qu * 8];
    *(uint4*)(ot + ((size_t)bh * L_ + q0b + row) * 32 + qu * 8) = v;
  }
}

// ---------------------------------------------------------------------------
extern "C" void kernel_launch(void* const* d_in, const int* in_sizes, int n_in,
                              void* d_out, int out_size, void* d_ws, size_t ws_size,
                              hipStream_t stream) {
  const float* x      = (const float*)d_in[0];
  const float* gamma  = (const float*)d_in[1];
  const float* beta   = (const float*)d_in[2];
  const float* dw     = (const float*)d_in[3];
  const float* qkv_w  = (const float*)d_in[4];
  const float* qkv_b  = (const float*)d_in[5];
  const float* out_w  = (const float*)d_in[6];
  const float* out_b  = (const float*)d_in[7];
  float* out = (float*)d_out;

  char* ws = (char*)d_ws;
  ushort* ht   = (ushort*)(ws);                   // 4 MiB @0  (dead after qkv)
  ushort* qtb  = (ushort*)(ws + (16u << 20));     // 4 MiB @16
  ushort* ktb  = (ushort*)(ws + (20u << 20));     // 4 MiB @20
  ushort* vbb  = (ushort*)(ws + (24u << 20));     // 4 MiB @24
  ushort* otb  = (ushort*)(ws);                   // 4 MiB @0  (reuse ht)
  ushort* wq   = (ushort*)(ws + (28u << 20));     // 384 KiB @28M
  ushort* wo   = (ushort*)(ws + (28u << 20) + (512u << 10));  // 128 KiB

  gnw_kernel<<<384, 512, 0, stream>>>(x, gamma, beta, dw,
                                      (const float4*)qkv_w, (const float4*)out_w,
                                      (uint2*)wq, (uint2*)wo, ht);
  qkv_fused_kernel<<<dim3(8, 8, B_), 256, 0, stream>>>(ht, wq, qkv_b, qtb, ktb, vbb);
  attn_mfma_kernel<<<512, 512, 0, stream>>>(qtb, ktb, vbb, otb);
  outconv_kernel<<<dim3(8, 4, B_), 256, 0, stream>>>(otb, wo, out_b, x, out);
}